// Round 6
// baseline (1373.330 us; speedup 1.0000x reference)
//
#include <hip/hip_runtime.h>
#include <math.h>

// LSTMEncoder: N=2048 rows, T=128, H=256. CU-LOCAL design:
// 128 blocks x 1024 threads (16 waves). Block owns 16 rows; wave w=cg owns
// 16 h-cols x 4 gates. FULL W slice persistent in VGPRs (36 frags = 144
// VGPR/lane, asm-pinned so the compiler cannot re-load it per step).
// h double-buffered in LDS; ONE __syncthreads per step; no cross-block
// communication at all (rows are independent). x-path + bias folded into a
// 9th K-tile of the MFMA.

#define TT 128
#define NH 256

typedef __attribute__((ext_vector_type(4))) float f32x4;
typedef __attribute__((ext_vector_type(8))) short s16x8;

__device__ __forceinline__ unsigned short f2bf(float x) {
    unsigned u = __float_as_uint(x);
    return (unsigned short)((u + 0x7FFFu + ((u >> 16) & 1u)) >> 16);
}

// wsW: 576 frags = (16 cg x 4 q x 9 kt) x 64 lanes x 8 bf16 (16B/lane)
__global__ void prep(const float* __restrict__ W_emb, const float* __restrict__ b_emb,
                     const float* __restrict__ W_ih,  const float* __restrict__ W_hh,
                     const float* __restrict__ b_ih,  const float* __restrict__ b_hh,
                     unsigned short* __restrict__ wsW)
{
    int tid = blockIdx.x * 256 + threadIdx.x;   // 0..36863
    int l   = tid & 63;
    int fid = tid >> 6;          // 0..575
    int kt  = fid % 9;
    int ntg = fid / 9;           // cg*4+q
    int q   = ntg & 3;
    int cg  = ntg >> 2;
    int g   = q * 256 + cg * 16 + (l & 15);   // gate row in W_hh/W_ih ordering
    union { unsigned short u16[8]; uint4 v; } pk;
    if (kt < 8) {
        int k0 = kt * 32 + (l >> 4) * 8;
        const float* src = &W_hh[g * 256 + k0];
        #pragma unroll
        for (int i = 0; i < 8; ++i) pk.u16[i] = f2bf(src[i]);
    } else {
        // folded x-path K-tile: [Wc[g][0..5], b_comb[g], 0] in k-slots 0..7
        #pragma unroll
        for (int i = 0; i < 8; ++i) pk.u16[i] = 0;
        if ((l >> 4) == 0) {
            float accf[6] = {0.f, 0.f, 0.f, 0.f, 0.f, 0.f};
            float accb = 0.f;
            for (int e = 0; e < 256; ++e) {
                float wv = W_ih[g * 256 + e];
                accb += wv * b_emb[e];
                #pragma unroll
                for (int f = 0; f < 6; ++f) accf[f] += wv * W_emb[e * 6 + f];
            }
            #pragma unroll
            for (int f = 0; f < 6; ++f) pk.u16[f] = f2bf(accf[f]);
            pk.u16[6] = f2bf(accb + b_ih[g] + b_hh[g]);
        }
    }
    *reinterpret_cast<uint4*>(&wsW[(size_t)fid * 512 + l * 8]) = pk.v;
}

__device__ __forceinline__ float sigmoidf_(float x) { return 1.f / (1.f + __expf(-x)); }
__device__ __forceinline__ float tanhf_(float x) {
    float e = __expf(-2.f * fabsf(x));
    float r = (1.f - e) / (1.f + e);
    return copysignf(r, x);
}

__device__ __forceinline__ s16x8 pack_x(const float* xin, int arow, int t, int lg) {
    union { unsigned short u16[8]; uint4 q; s16x8 s; } pk;
    pk.q = (uint4){0u, 0u, 0u, 0u};
    if (lg == 0) {
        const float* xp = xin + ((size_t)arow * TT + t) * 6;
        #pragma unroll
        for (int f = 0; f < 6; ++f) pk.u16[f] = f2bf(xp[f]);
        pk.u16[6] = 0x3F80;  // 1.0 -> bias slot
    }
    return pk.s;
}

__global__ __launch_bounds__(1024, 4)
void lstm_main(const float* __restrict__ xin, const unsigned short* __restrict__ wsW,
               float* __restrict__ out)
{
    // h double buffer: rows padded to 264 bf16 (528B stride -> only 2-way bank alias)
    __shared__ __align__(16) unsigned short hsh[2][16][264];

    const int tid = threadIdx.x;
    const int cg  = tid >> 6;                 // wave id == column group 0..15
    const int l   = tid & 63;
    const int l16 = l & 15,  lg = l >> 4;
    const int n0  = blockIdx.x * 16;          // block's 16 rows
    const int j   = cg * 16 + l16;            // lane's global h column
    const int arow  = n0 + l16;               // A-frag row (M index = l16)
    const int crow0 = n0 + lg * 4;            // C rows base (rows lg*4..+3)

    // ---- persistent W fragments: 36 x s16x8 = 144 VGPR, loaded ONCE ----
    s16x8 Wf[4][9];
    #pragma unroll
    for (int q = 0; q < 4; ++q)
        #pragma unroll
        for (int kt = 0; kt < 9; ++kt)
            Wf[q][kt] = *reinterpret_cast<const s16x8*>(
                &wsW[(size_t)((cg * 4 + q) * 9 + kt) * 512 + l * 8]);
    // pin in registers: asm "writes" the value, so reload/remat is illegal
    #pragma unroll
    for (int q = 0; q < 4; ++q)
        #pragma unroll
        for (int kt = 0; kt < 9; ++kt)
            asm volatile("" : "+v"(Wf[q][kt]));

    s16x8 xa = pack_x(xin, arow, 0, lg);
    float c_[4] = {0.f, 0.f, 0.f, 0.f};

    for (int t = 0; t < TT; ++t) {
        f32x4 acc[4];
        #pragma unroll
        for (int q = 0; q < 4; ++q) acc[q] = (f32x4){0.f, 0.f, 0.f, 0.f};

        if (t > 0) {
            const int cur = (t - 1) & 1;
            s16x8 a[8];
            #pragma unroll
            for (int kt = 0; kt < 8; ++kt)
                a[kt] = *reinterpret_cast<const s16x8*>(&hsh[cur][l16][kt * 32 + lg * 8]);
            #pragma unroll
            for (int kt = 0; kt < 8; ++kt)
                #pragma unroll
                for (int q = 0; q < 4; ++q)
                    acc[q] = __builtin_amdgcn_mfma_f32_16x16x32_bf16(a[kt], Wf[q][kt], acc[q], 0, 0, 0);
        }
        // x-path + bias as 9th K-tile
        #pragma unroll
        for (int q = 0; q < 4; ++q)
            acc[q] = __builtin_amdgcn_mfma_f32_16x16x32_bf16(xa, Wf[q][8], acc[q], 0, 0, 0);

        if (t + 1 < TT) xa = pack_x(xin, arow, t + 1, lg);  // prefetch (cached)

        // ---- lane-local elementwise: rows crow0..+3, col j, gates in-lane ----
        float hn[4];
        #pragma unroll
        for (int r = 0; r < 4; ++r) {
            float gi = sigmoidf_(acc[0][r]);
            float gf = sigmoidf_(acc[1][r]);
            float gg = tanhf_  (acc[2][r]);
            float go = sigmoidf_(acc[3][r]);
            float cn = fmaf(gf, c_[r], gi * gg);
            c_[r] = cn;
            hn[r] = go * tanhf_(cn);
        }

        if (t < TT - 1) {
            const int nxt = t & 1;
            #pragma unroll
            for (int r = 0; r < 4; ++r)
                hsh[nxt][lg * 4 + r][j] = f2bf(hn[r]);
        }

        // out stores: 16 lanes x 4B contiguous = 64B segments, off critical path
        #pragma unroll
        for (int r = 0; r < 4; ++r)
            out[((size_t)(crow0 + r) * TT + t) * NH + j] = hn[r];

        if (t < TT - 1) __syncthreads();   // publish h(t); protect cur from t+1 writes
    }
}

extern "C" void kernel_launch(void* const* d_in, const int* in_sizes, int n_in,
                              void* d_out, int out_size, void* d_ws, size_t ws_size,
                              hipStream_t stream)
{
    const float* xin   = (const float*)d_in[0];
    const float* W_emb = (const float*)d_in[1];
    const float* b_emb = (const float*)d_in[2];
    const float* W_ih  = (const float*)d_in[3];
    const float* W_hh  = (const float*)d_in[4];
    const float* b_ih  = (const float*)d_in[5];
    const float* b_hh  = (const float*)d_in[6];
    float* out = (float*)d_out;

    unsigned short* wsW = (unsigned short*)d_ws;

    prep<<<144, 256, 0, stream>>>(W_emb, b_emb, W_ih, W_hh, b_ih, b_hh, wsW);
    lstm_main<<<128, 1024, 0, stream>>>(xin, wsW, out);
}

// Round 9
// 1044.645 us; speedup vs baseline: 1.3146x; 1.3146x over previous
//
#include <hip/hip_runtime.h>
#include <math.h>

// LSTMEncoder N=2048, T=128, H=256. 4-way column-split, W register-resident.
// 256 blocks x 1024 thr (16 waves) = 1 block/CU, all co-resident.
// Block (q4 = bid>>6, g = bid&63): rows n0=g*32..+31, h-cols q4*64..+63.
// Wave w owns one 16-wide n-tile: n = c*4+q (c=h-col, q=gate i,f,g,o) ->
// lane-local gates via quad_perm broadcast. W slice = 9 frags (8 K-tiles of
// W_hh + folded x/bias tile) = 36 VGPR, loaded once (volatile asm, no remat).
// Per-step h exchange through Infinity Cache with TAGGED 16B units
// {3 dwords = 6 bf16 h, 1 dword tag=t}: data stored as 3 scalar dwords
// (sc0 sc1), ONE vmcnt(0) drain, then the tag dword (sc0 sc1) -> tag valid
// implies data valid at MALL. Consumers spin with a single 16B load (fused
// poll+data). Double-buffered by t parity; pub memset to 0xFF per launch so
// no stale tag can match. Drain also orders t vs t+2 same-slot stores.

#define TT 128
#define NH 256

typedef __attribute__((ext_vector_type(4))) float f32x4;
typedef __attribute__((ext_vector_type(8))) short s16x8;
typedef union { uint4 u4; s16x8 s; unsigned u[4]; } frag_u;

// ws layout (bytes):
//   wsW [0, 589824)        : 576 frags x 64 lanes x 16B
//   pub [589824, 3391488)  : [2 parity][256 bid][342 units x 16B]
#define OFF_PUB   589824
#define PUB_UNITS 342
#define PUB_STRIDE (PUB_UNITS * 16)
#define PUB_BYTES (2 * 256 * PUB_STRIDE)

__device__ __forceinline__ unsigned short f2bf(float x) {
    unsigned u = __float_as_uint(x);
    return (unsigned short)((u + 0x7FFFu + ((u >> 16) & 1u)) >> 16);
}
__device__ __forceinline__ float bf2f(unsigned b) {
    return __uint_as_float(b << 16);
}

__global__ void prep(const float* __restrict__ W_emb, const float* __restrict__ b_emb,
                     const float* __restrict__ W_ih,  const float* __restrict__ W_hh,
                     const float* __restrict__ b_ih,  const float* __restrict__ b_hh,
                     unsigned short* __restrict__ wsW)
{
    int tid = blockIdx.x * 256 + threadIdx.x;   // 0..36863
    if (tid >= 36864) return;
    int l    = tid & 63;
    int fid  = tid >> 6;          // 0..575
    int kt   = fid % 9;
    int cg16 = fid / 9;           // n-tile id 0..63  (== q4*16 + w)
    int l16  = l & 15, lg = l >> 4;
    int c    = l16 >> 2, q = l16 & 3;
    int col  = cg16 * 4 + c;      // h column
    int grow = q * 256 + col;     // gate row (i,f,g,o blocks of 256)
    union { unsigned short u16[8]; uint4 v; } pk;
    if (kt < 8) {
        int k0 = kt * 32 + lg * 8;
        const float* src = &W_hh[grow * 256 + k0];
        #pragma unroll
        for (int i = 0; i < 8; ++i) pk.u16[i] = f2bf(src[i]);
    } else {
        #pragma unroll
        for (int i = 0; i < 8; ++i) pk.u16[i] = 0;
        if (lg == 0) {
            float accf[6] = {0.f, 0.f, 0.f, 0.f, 0.f, 0.f};
            float accb = 0.f;
            for (int e = 0; e < 256; ++e) {
                float wv = W_ih[grow * 256 + e];
                accb += wv * b_emb[e];
                #pragma unroll
                for (int f = 0; f < 6; ++f) accf[f] += wv * W_emb[e * 6 + f];
            }
            #pragma unroll
            for (int f = 0; f < 6; ++f) pk.u16[f] = f2bf(accf[f]);
            pk.u16[6] = f2bf(accb + b_ih[grow] + b_hh[grow]);
        }
    }
    *reinterpret_cast<uint4*>(&wsW[(size_t)fid * 512 + l * 8]) = pk.v;
}

__device__ __forceinline__ float sigmoidf_(float x) { return 1.f / (1.f + __expf(-x)); }
__device__ __forceinline__ float tanhf_(float x) {
    float e = __expf(-2.f * fabsf(x));
    float r = (1.f - e) / (1.f + e);
    return copysignf(r, x);
}

__device__ __forceinline__ uint4 ld16_dev(const void* p) {
    uint4 v;
    asm volatile("global_load_dwordx4 %0, %1, off sc0 sc1\n\ts_waitcnt vmcnt(0)"
                 : "=v"(v) : "v"(p) : "memory");
    return v;
}
__device__ __forceinline__ void st4_dev(void* p, unsigned v) {
    asm volatile("global_store_dword %0, %1, off sc0 sc1" :: "v"(p), "v"(v) : "memory");
}

__global__ __launch_bounds__(1024, 4)
void lstm_main(const float* __restrict__ xin, const unsigned short* __restrict__ wsW,
               float* __restrict__ out, char* __restrict__ pub)
{
    __shared__ __align__(16) unsigned short hsh[32][264];  // 528B row stride

    const int tid = threadIdx.x;
    const int w   = tid >> 6, l = tid & 63;
    const int l16 = l & 15,  lg = l >> 4;
    const int c   = l16 >> 2, q = l16 & 3;
    const int bid = blockIdx.x;
    const int q4  = bid >> 6;            // column quarter 0..3
    const int g   = bid & 63;            // row group
    const int n0  = g * 32;
    const int j   = q4 * 64 + w * 4 + c; // lane's h column
    const int cg16 = q4 * 16 + w;

    // ---- persistent W: 9 frags = 36 VGPR, volatile-asm loads (no remat) ----
    frag_u Wf[9];
    #pragma unroll
    for (int kt = 0; kt < 9; ++kt) {
        const unsigned short* p = &wsW[(size_t)(cg16 * 9 + kt) * 512 + l * 8];
        asm volatile("global_load_dwordx4 %0, %1, off" : "=v"(Wf[kt].u4) : "v"(p));
    }
    asm volatile("s_waitcnt vmcnt(0)" ::: "memory");

    float c0_[4] = {0.f, 0.f, 0.f, 0.f};   // cell state rows lg*4+r, m-tile 0
    float c1_[4] = {0.f, 0.f, 0.f, 0.f};   // m-tile 1

    for (int t = 0; t < TT; ++t) {
        // ---- x/bias A-frags for this t (cached loads; overlap the spin) ----
        frag_u xa0, xa1;
        xa0.u4 = (uint4){0u, 0u, 0u, 0u};
        xa1.u4 = (uint4){0u, 0u, 0u, 0u};
        if (lg == 0) {
            union { unsigned short u16[8]; uint4 v; } pk;
            const float* xp0 = xin + ((size_t)(n0 + l16) * TT + t) * 6;
            #pragma unroll
            for (int f = 0; f < 6; ++f) pk.u16[f] = f2bf(xp0[f]);
            pk.u16[6] = 0x3F80; pk.u16[7] = 0;
            xa0.u4 = pk.v;
            const float* xp1 = xin + ((size_t)(n0 + 16 + l16) * TT + t) * 6;
            #pragma unroll
            for (int f = 0; f < 6; ++f) pk.u16[f] = f2bf(xp1[f]);
            pk.u16[6] = 0x3F80; pk.u16[7] = 0;
            xa1.u4 = pk.v;
        }

        // ---- stage: spin on partner tagged units, write into LDS ----
        if (t > 0) {
            const int want = t - 1;
            const char* base = pub + (size_t)(want & 1) * 256 * PUB_STRIDE;
            #pragma unroll
            for (int pass = 0; pass < 2; ++pass) {
                int iu = tid + pass * 1024;
                if (iu < 3 * PUB_UNITS) {
                    int p_ord = iu / PUB_UNITS;
                    int u     = iu - p_ord * PUB_UNITS;
                    int p     = p_ord + (p_ord >= q4 ? 1 : 0);   // partner quarter
                    const char* src = base + (size_t)(g + 64 * p) * PUB_STRIDE + u * 16;
                    uint4 v; int it = 0;
                    do { v = ld16_dev(src); } while ((int)v.w != want && ++it < (1 << 15));
                    const int D0 = 3 * u;                         // dword index in [32][32]
                    {   int r = D0 >> 5, d = D0 & 31;
                        *reinterpret_cast<unsigned*>(&hsh[r][p * 64 + 2 * d]) = v.x; }
                    if (D0 + 1 < 1024) {
                        int r = (D0 + 1) >> 5, d = (D0 + 1) & 31;
                        *reinterpret_cast<unsigned*>(&hsh[r][p * 64 + 2 * d]) = v.y; }
                    if (D0 + 2 < 1024) {
                        int r = (D0 + 2) >> 5, d = (D0 + 2) & 31;
                        *reinterpret_cast<unsigned*>(&hsh[r][p * 64 + 2 * d]) = v.z; }
                }
            }
        }
        __syncthreads();   // BAR1: staged h(t-1) visible (no-op work at t=0)

        // ---- recurrent GEMM + x-tile ----
        f32x4 acc0 = (f32x4){0.f, 0.f, 0.f, 0.f};
        f32x4 acc1 = (f32x4){0.f, 0.f, 0.f, 0.f};
        if (t > 0) {
            #pragma unroll
            for (int kt = 0; kt < 8; ++kt) {
                s16x8 a0 = *reinterpret_cast<const s16x8*>(&hsh[l16     ][kt * 32 + lg * 8]);
                s16x8 a1 = *reinterpret_cast<const s16x8*>(&hsh[16 + l16][kt * 32 + lg * 8]);
                acc0 = __builtin_amdgcn_mfma_f32_16x16x32_bf16(a0, Wf[kt].s, acc0, 0, 0, 0);
                acc1 = __builtin_amdgcn_mfma_f32_16x16x32_bf16(a1, Wf[kt].s, acc1, 0, 0, 0);
            }
        }
        acc0 = __builtin_amdgcn_mfma_f32_16x16x32_bf16(xa0.s, Wf[8].s, acc0, 0, 0, 0);
        acc1 = __builtin_amdgcn_mfma_f32_16x16x32_bf16(xa1.s, Wf[8].s, acc1, 0, 0, 0);
        __syncthreads();   // BAR2: all LDS reads of h(t-1) complete

        // ---- elementwise via quad_perm gate broadcast; keep only r==q row ----
        float hsel0 = 0.f, hsel1 = 0.f;
        #pragma unroll
        for (int r = 0; r < 4; ++r) {
            int av = __float_as_int(acc0[r]);
            float vi = __int_as_float(__builtin_amdgcn_ds_swizzle(av, 0x8000));
            float vf = __int_as_float(__builtin_amdgcn_ds_swizzle(av, 0x8055));
            float vg = __int_as_float(__builtin_amdgcn_ds_swizzle(av, 0x80AA));
            float vo = __int_as_float(__builtin_amdgcn_ds_swizzle(av, 0x80FF));
            float cn = fmaf(sigmoidf_(vf), c0_[r], sigmoidf_(vi) * tanhf_(vg));
            c0_[r] = cn;
            float hv = sigmoidf_(vo) * tanhf_(cn);
            if (r == q) hsel0 = hv;
        }
        #pragma unroll
        for (int r = 0; r < 4; ++r) {
            int av = __float_as_int(acc1[r]);
            float vi = __int_as_float(__builtin_amdgcn_ds_swizzle(av, 0x8000));
            float vf = __int_as_float(__builtin_amdgcn_ds_swizzle(av, 0x8055));
            float vg = __int_as_float(__builtin_amdgcn_ds_swizzle(av, 0x80AA));
            float vo = __int_as_float(__builtin_amdgcn_ds_swizzle(av, 0x80FF));
            float cn = fmaf(sigmoidf_(vf), c1_[r], sigmoidf_(vi) * tanhf_(vg));
            c1_[r] = cn;
            float hv = sigmoidf_(vo) * tanhf_(cn);
            if (r == q) hsel1 = hv;
        }
        // write own h(t) into LDS (lane covers row lg*4+q of each m-tile, col j)
        hsh[lg * 4 + q     ][j] = f2bf(hsel0);
        hsh[16 + lg * 4 + q][j] = f2bf(hsel1);
        __syncthreads();   // BAR3: own-quarter h(t) complete in LDS

        // ---- publish: data dwords + out stores -> drain -> tag dwords ----
        char* dst = nullptr;
        if (t < TT - 1 && tid < PUB_UNITS) {
            const int u = tid, D0 = 3 * u;
            unsigned px, py = 0, pz = 0;
            { int r = D0 >> 5, d = D0 & 31;
              px = *reinterpret_cast<const unsigned*>(&hsh[r][q4 * 64 + 2 * d]); }
            if (D0 + 1 < 1024) { int r = (D0 + 1) >> 5, d = (D0 + 1) & 31;
              py = *reinterpret_cast<const unsigned*>(&hsh[r][q4 * 64 + 2 * d]); }
            if (D0 + 2 < 1024) { int r = (D0 + 2) >> 5, d = (D0 + 2) & 31;
              pz = *reinterpret_cast<const unsigned*>(&hsh[r][q4 * 64 + 2 * d]); }
            dst = pub + ((size_t)(t & 1) * 256 + bid) * PUB_STRIDE + u * 16;
            st4_dev(dst,     px);
            st4_dev(dst + 4, py);
            st4_dev(dst + 8, pz);
        }
        {
            int r = tid >> 5, d = tid & 31;
            unsigned hv = *reinterpret_cast<const unsigned*>(&hsh[r][q4 * 64 + 2 * d]);
            float2 ov = make_float2(bf2f(hv & 0xffffu), bf2f(hv >> 16));
            *reinterpret_cast<float2*>(
                &out[((size_t)(n0 + r) * TT + t) * NH + q4 * 64 + 2 * d]) = ov;
        }
        asm volatile("s_waitcnt vmcnt(0)" ::: "memory");  // data at MALL before tag
        if (t < TT - 1 && tid < PUB_UNITS)
            st4_dev(dst + 12, (unsigned)t);
        // no barrier: next staging writes partner cols only (disjoint from own-
        // col reads above); GEMM reads of h(t-1) were fenced by BAR2.
    }
}

extern "C" void kernel_launch(void* const* d_in, const int* in_sizes, int n_in,
                              void* d_out, int out_size, void* d_ws, size_t ws_size,
                              hipStream_t stream)
{
    const float* xin   = (const float*)d_in[0];
    const float* W_emb = (const float*)d_in[1];
    const float* b_emb = (const float*)d_in[2];
    const float* W_ih  = (const float*)d_in[3];
    const float* W_hh  = (const float*)d_in[4];
    const float* b_ih  = (const float*)d_in[5];
    const float* b_hh  = (const float*)d_in[6];
    float* out = (float*)d_out;

    unsigned short* wsW = (unsigned short*)d_ws;
    char* pub = (char*)d_ws + OFF_PUB;

    hipMemsetAsync(pub, 0xFF, PUB_BYTES, stream);   // tags -> -1 (never a valid t)
    prep<<<144, 256, 0, stream>>>(W_emb, b_emb, W_ih, W_hh, b_ih, b_hh, wsW);
    lstm_main<<<256, 1024, 0, stream>>>(xin, wsW, out, pub);
}

// Round 11
// 832.004 us; speedup vs baseline: 1.6506x; 1.2556x over previous
//
#include <hip/hip_runtime.h>
#include <math.h>

// LSTMEncoder N=2048, T=128, H=256. 4-way column-split, W register-resident.
// 256 blocks x 1024 thr (16 waves). Block (q4=bid>>6, g=bid&63): rows g*32..+31,
// h-cols q4*64..+63. Wave w owns one 16-wide n-tile: n=c*4+q (c=h-col, q=gate).
// W slice = 9 frags (8 K-tiles W_hh + folded x/bias tile) = 36 VGPR, loaded once.
// Exchange via Infinity Cache, TAGGED 16B units {3 dwords=6 bf16, tag=t}:
// data dwords -> one vmcnt drain -> tag dword (tag valid => data valid at MALL).
// Consumers ISSUE unit loads early, overlap x-pack, ONE check, then
// s_sleep-backoff retries only for stale lanes (kills the R9 poll storm).
// EW: quad-transpose via templated ds_swizzle (literal patterns) + cndmask ->
// each lane computes only its own row q (5 transcendental pairs per m-tile).

#define TT 128
#define NH 256

typedef __attribute__((ext_vector_type(4))) float f32x4;
typedef __attribute__((ext_vector_type(8))) short s16x8;
typedef union { uint4 u4; s16x8 s; unsigned u[4]; } frag_u;

// ws layout (bytes):
//   wsW [0, 589824)        : 576 frags x 64 lanes x 16B
//   pub [589824, 3391488)  : [2 parity][256 bid][342 units x 16B]
#define OFF_PUB   589824
#define PUB_UNITS 342
#define NUNITS3   (3 * PUB_UNITS)
#define PUB_STRIDE (PUB_UNITS * 16)
#define PUB_BYTES (2 * 256 * PUB_STRIDE)

__device__ __forceinline__ unsigned short f2bf(float x) {
    unsigned u = __float_as_uint(x);
    return (unsigned short)((u + 0x7FFFu + ((u >> 16) & 1u)) >> 16);
}
__device__ __forceinline__ float bf2f(unsigned b) {
    return __uint_as_float(b << 16);
}

template<int PAT>
__device__ __forceinline__ float qswz(float x) {
    return __int_as_float(__builtin_amdgcn_ds_swizzle(__float_as_int(x), PAT));
}

__global__ void prep(const float* __restrict__ W_emb, const float* __restrict__ b_emb,
                     const float* __restrict__ W_ih,  const float* __restrict__ W_hh,
                     const float* __restrict__ b_ih,  const float* __restrict__ b_hh,
                     unsigned short* __restrict__ wsW)
{
    int tid = blockIdx.x * 256 + threadIdx.x;   // 0..36863
    if (tid >= 36864) return;
    int l    = tid & 63;
    int fid  = tid >> 6;          // 0..575
    int kt   = fid % 9;
    int cg16 = fid / 9;           // n-tile id 0..63  (== q4*16 + w)
    int l16  = l & 15, lg = l >> 4;
    int c    = l16 >> 2, q = l16 & 3;
    int col  = cg16 * 4 + c;      // h column
    int grow = q * 256 + col;     // gate row (i,f,g,o blocks of 256)
    union { unsigned short u16[8]; uint4 v; } pk;
    if (kt < 8) {
        int k0 = kt * 32 + lg * 8;
        const float* src = &W_hh[grow * 256 + k0];
        #pragma unroll
        for (int i = 0; i < 8; ++i) pk.u16[i] = f2bf(src[i]);
    } else {
        #pragma unroll
        for (int i = 0; i < 8; ++i) pk.u16[i] = 0;
        if (lg == 0) {
            float accf[6] = {0.f, 0.f, 0.f, 0.f, 0.f, 0.f};
            float accb = 0.f;
            for (int e = 0; e < 256; ++e) {
                float wv = W_ih[grow * 256 + e];
                accb += wv * b_emb[e];
                #pragma unroll
                for (int f = 0; f < 6; ++f) accf[f] += wv * W_emb[e * 6 + f];
            }
            #pragma unroll
            for (int f = 0; f < 6; ++f) pk.u16[f] = f2bf(accf[f]);
            pk.u16[6] = f2bf(accb + b_ih[grow] + b_hh[grow]);
        }
    }
    *reinterpret_cast<uint4*>(&wsW[(size_t)fid * 512 + l * 8]) = pk.v;
}

__device__ __forceinline__ float sigmoidf_(float x) { return 1.f / (1.f + __expf(-x)); }
__device__ __forceinline__ float tanhf_(float x) {
    float e = __expf(-2.f * fabsf(x));
    float r = (1.f - e) / (1.f + e);
    return copysignf(r, x);
}

__device__ __forceinline__ uint4 ld16_dev(const void* p) {   // fused load+wait
    uint4 v;
    asm volatile("global_load_dwordx4 %0, %1, off sc0 sc1\n\ts_waitcnt vmcnt(0)"
                 : "=v"(v) : "v"(p) : "memory");
    return v;
}
__device__ __forceinline__ void st4_dev(void* p, unsigned v) {
    asm volatile("global_store_dword %0, %1, off sc0 sc1" :: "v"(p), "v"(v) : "memory");
}

// quad-transpose gather: from acc (4 gate regs, quad rows) pick this lane's row
__device__ __forceinline__ void qgather(const f32x4& acc, bool qb0, bool qb1, float X[4]) {
    float g0, g1, g2, g3, x01, x23;
    g0 = qswz<0x8000>(acc[0]); g1 = qswz<0x8000>(acc[1]);
    g2 = qswz<0x8000>(acc[2]); g3 = qswz<0x8000>(acc[3]);
    x01 = qb0 ? g1 : g0; x23 = qb0 ? g3 : g2; X[0] = qb1 ? x23 : x01;
    g0 = qswz<0x8055>(acc[0]); g1 = qswz<0x8055>(acc[1]);
    g2 = qswz<0x8055>(acc[2]); g3 = qswz<0x8055>(acc[3]);
    x01 = qb0 ? g1 : g0; x23 = qb0 ? g3 : g2; X[1] = qb1 ? x23 : x01;
    g0 = qswz<0x80AA>(acc[0]); g1 = qswz<0x80AA>(acc[1]);
    g2 = qswz<0x80AA>(acc[2]); g3 = qswz<0x80AA>(acc[3]);
    x01 = qb0 ? g1 : g0; x23 = qb0 ? g3 : g2; X[2] = qb1 ? x23 : x01;
    g0 = qswz<0x80FF>(acc[0]); g1 = qswz<0x80FF>(acc[1]);
    g2 = qswz<0x80FF>(acc[2]); g3 = qswz<0x80FF>(acc[3]);
    x01 = qb0 ? g1 : g0; x23 = qb0 ? g3 : g2; X[3] = qb1 ? x23 : x01;
}

__global__ __launch_bounds__(1024, 4)
void lstm_main(const float* __restrict__ xin, const unsigned short* __restrict__ wsW,
               float* __restrict__ out, char* __restrict__ pub)
{
    __shared__ __align__(16) unsigned short hsh[32][264];  // 528B row stride

    const int tid = threadIdx.x;
    const int w   = tid >> 6, l = tid & 63;
    const int l16 = l & 15,  lg = l >> 4;
    const int c   = l16 >> 2, q = l16 & 3;
    const bool qb0 = (q & 1), qb1 = (q & 2);
    const int bid = blockIdx.x;
    const int q4  = bid >> 6;            // column quarter 0..3
    const int g   = bid & 63;            // row group
    const int n0  = g * 32;
    const int j   = q4 * 64 + w * 4 + c; // lane's h column
    const int cg16 = q4 * 16 + w;

    // ---- persistent W: 9 frags = 36 VGPR, volatile-asm loads (no remat) ----
    frag_u Wf[9];
    #pragma unroll
    for (int kt = 0; kt < 9; ++kt) {
        const unsigned short* p = &wsW[(size_t)(cg16 * 9 + kt) * 512 + l * 8];
        asm volatile("global_load_dwordx4 %0, %1, off" : "=v"(Wf[kt].u4) : "v"(p));
    }
    asm volatile("s_waitcnt vmcnt(0)" ::: "memory");

    float cm0 = 0.f, cm1 = 0.f;   // cell state for my row (lg*4+q), m-tile 0/1

    // per-thread staged-unit geometry (constant across t)
    const int iuA = tid;                 // < 1026 always
    const int iuB = tid + 1024;          // valid only for tid<2
    const int pA_ord = iuA / PUB_UNITS, uA = iuA - pA_ord * PUB_UNITS;
    const int pB_ord = iuB / PUB_UNITS, uB = iuB - pB_ord * PUB_UNITS;
    const int pA = pA_ord + (pA_ord >= q4 ? 1 : 0);
    const int pB = pB_ord + (pB_ord >= q4 ? 1 : 0);

    for (int t = 0; t < TT; ++t) {
        const int want = t - 1;
        uint4 vA = make_uint4(0u, 0u, 0u, 0u);
        uint4 vB = make_uint4(0u, 0u, 0u, (unsigned)want);   // ok by default
        const char* srcA = nullptr; const char* srcB = nullptr;

        // ---- A. issue partner unit loads (no wait) ----
        if (t > 0) {
            const char* base = pub + (size_t)(want & 1) * 256 * PUB_STRIDE;
            srcA = base + (size_t)(g + 64 * pA) * PUB_STRIDE + uA * 16;
            asm volatile("global_load_dwordx4 %0, %1, off sc0 sc1"
                         : "=v"(vA) : "v"(srcA) : "memory");
            if (iuB < NUNITS3) {
                srcB = base + (size_t)(g + 64 * pB) * PUB_STRIDE + uB * 16;
                asm volatile("global_load_dwordx4 %0, %1, off sc0 sc1"
                             : "=v"(vB) : "v"(srcB) : "memory");
            }
        }

        // ---- B. x/bias A-frags (cached loads; overlap the in-flight sweep) ----
        frag_u xa0, xa1;
        xa0.u4 = (uint4){0u, 0u, 0u, 0u};
        xa1.u4 = (uint4){0u, 0u, 0u, 0u};
        if (lg == 0) {
            union { unsigned short u16[8]; uint4 v; } pk;
            const float* xp0 = xin + ((size_t)(n0 + l16) * TT + t) * 6;
            #pragma unroll
            for (int f = 0; f < 6; ++f) pk.u16[f] = f2bf(xp0[f]);
            pk.u16[6] = 0x3F80; pk.u16[7] = 0;
            xa0.u4 = pk.v;
            const float* xp1 = xin + ((size_t)(n0 + 16 + l16) * TT + t) * 6;
            #pragma unroll
            for (int f = 0; f < 6; ++f) pk.u16[f] = f2bf(xp1[f]);
            pk.u16[6] = 0x3F80; pk.u16[7] = 0;
            xa1.u4 = pk.v;
        }

        // ---- C. check tags once; retry only stale lanes with backoff ----
        if (t > 0) {
            asm volatile("s_waitcnt vmcnt(0)" ::: "memory");
            __builtin_amdgcn_sched_barrier(0);   // rule #18: no hoisting past wait
            bool okA = ((int)vA.w == want);
            bool okB = (iuB >= NUNITS3) || ((int)vB.w == want);
            int it = 0;
            while (__ballot(!(okA && okB)) != 0ull) {
                __builtin_amdgcn_s_sleep(1);
                if (!okA) { vA = ld16_dev(srcA); okA = ((int)vA.w == want); }
                if (!okB) { vB = ld16_dev(srcB); okB = ((int)vB.w == want); }
                if (++it > (1 << 13)) break;     // fail loud via absmax, not hang
            }
            // stage unit A (all threads) and unit B (tid<2)
            {
                const int D0 = 3 * uA;
                {   int r = D0 >> 5, d = D0 & 31;
                    *reinterpret_cast<unsigned*>(&hsh[r][pA * 64 + 2 * d]) = vA.x; }
                if (D0 + 1 < 1024) { int r = (D0 + 1) >> 5, d = (D0 + 1) & 31;
                    *reinterpret_cast<unsigned*>(&hsh[r][pA * 64 + 2 * d]) = vA.y; }
                if (D0 + 2 < 1024) { int r = (D0 + 2) >> 5, d = (D0 + 2) & 31;
                    *reinterpret_cast<unsigned*>(&hsh[r][pA * 64 + 2 * d]) = vA.z; }
            }
            if (iuB < NUNITS3) {
                const int D0 = 3 * uB;
                {   int r = D0 >> 5, d = D0 & 31;
                    *reinterpret_cast<unsigned*>(&hsh[r][pB * 64 + 2 * d]) = vB.x; }
                if (D0 + 1 < 1024) { int r = (D0 + 1) >> 5, d = (D0 + 1) & 31;
                    *reinterpret_cast<unsigned*>(&hsh[r][pB * 64 + 2 * d]) = vB.y; }
                if (D0 + 2 < 1024) { int r = (D0 + 2) >> 5, d = (D0 + 2) & 31;
                    *reinterpret_cast<unsigned*>(&hsh[r][pB * 64 + 2 * d]) = vB.z; }
            }
        }
        __syncthreads();   // BAR1: staged h(t-1) visible

        // ---- D. recurrent GEMM + x-tile ----
        f32x4 acc0 = (f32x4){0.f, 0.f, 0.f, 0.f};
        f32x4 acc1 = (f32x4){0.f, 0.f, 0.f, 0.f};
        if (t > 0) {
            #pragma unroll
            for (int kt = 0; kt < 8; ++kt) {
                s16x8 a0 = *reinterpret_cast<const s16x8*>(&hsh[l16     ][kt * 32 + lg * 8]);
                s16x8 a1 = *reinterpret_cast<const s16x8*>(&hsh[16 + l16][kt * 32 + lg * 8]);
                acc0 = __builtin_amdgcn_mfma_f32_16x16x32_bf16(a0, Wf[kt].s, acc0, 0, 0, 0);
                acc1 = __builtin_amdgcn_mfma_f32_16x16x32_bf16(a1, Wf[kt].s, acc1, 0, 0, 0);
            }
        }
        acc0 = __builtin_amdgcn_mfma_f32_16x16x32_bf16(xa0.s, Wf[8].s, acc0, 0, 0, 0);
        acc1 = __builtin_amdgcn_mfma_f32_16x16x32_bf16(xa1.s, Wf[8].s, acc1, 0, 0, 0);
        __syncthreads();   // BAR2: all LDS reads of h(t-1) complete

        // ---- E. quad-transpose gather + elementwise for OWN row q only ----
        float hn0, hn1;
        {
            float X[4];
            qgather(acc0, qb0, qb1, X);
            float cn = fmaf(sigmoidf_(X[1]), cm0, sigmoidf_(X[0]) * tanhf_(X[2]));
            cm0 = cn;
            hn0 = sigmoidf_(X[3]) * tanhf_(cn);
            qgather(acc1, qb0, qb1, X);
            cn = fmaf(sigmoidf_(X[1]), cm1, sigmoidf_(X[0]) * tanhf_(X[2]));
            cm1 = cn;
            hn1 = sigmoidf_(X[3]) * tanhf_(cn);
        }
        // write own h(t) into LDS (lane covers row lg*4+q of each m-tile, col j)
        hsh[lg * 4 + q     ][j] = f2bf(hn0);
        hsh[16 + lg * 4 + q][j] = f2bf(hn1);
        __syncthreads();   // BAR3: own-quarter h(t) complete in LDS

        // ---- F. publish: data dwords + out stores -> drain -> tag dwords ----
        char* dst = nullptr;
        if (t < TT - 1 && tid < PUB_UNITS) {
            const int u = tid, D0 = 3 * u;
            unsigned px, py = 0, pz = 0;
            { int r = D0 >> 5, d = D0 & 31;
              px = *reinterpret_cast<const unsigned*>(&hsh[r][q4 * 64 + 2 * d]); }
            if (D0 + 1 < 1024) { int r = (D0 + 1) >> 5, d = (D0 + 1) & 31;
              py = *reinterpret_cast<const unsigned*>(&hsh[r][q4 * 64 + 2 * d]); }
            if (D0 + 2 < 1024) { int r = (D0 + 2) >> 5, d = (D0 + 2) & 31;
              pz = *reinterpret_cast<const unsigned*>(&hsh[r][q4 * 64 + 2 * d]); }
            dst = pub + ((size_t)(t & 1) * 256 + bid) * PUB_STRIDE + u * 16;
            st4_dev(dst,     px);
            st4_dev(dst + 4, py);
            st4_dev(dst + 8, pz);
        }
        {
            int r = tid >> 5, d = tid & 31;
            unsigned hv = *reinterpret_cast<const unsigned*>(&hsh[r][q4 * 64 + 2 * d]);
            float2 ov = make_float2(bf2f(hv & 0xffffu), bf2f(hv >> 16));
            *reinterpret_cast<float2*>(
                &out[((size_t)(n0 + r) * TT + t) * NH + q4 * 64 + 2 * d]) = ov;
        }
        asm volatile("s_waitcnt vmcnt(0)" ::: "memory");  // data at MALL before tag
        if (t < TT - 1 && tid < PUB_UNITS)
            st4_dev(dst + 12, (unsigned)t);
        // no barrier: next staging writes partner cols only; own-col reads above
        // are protected by BAR1/BAR2 of the next iteration.
    }
}

extern "C" void kernel_launch(void* const* d_in, const int* in_sizes, int n_in,
                              void* d_out, int out_size, void* d_ws, size_t ws_size,
                              hipStream_t stream)
{
    const float* xin   = (const float*)d_in[0];
    const float* W_emb = (const float*)d_in[1];
    const float* b_emb = (const float*)d_in[2];
    const float* W_ih  = (const float*)d_in[3];
    const float* W_hh  = (const float*)d_in[4];
    const float* b_ih  = (const float*)d_in[5];
    const float* b_hh  = (const float*)d_in[6];
    float* out = (float*)d_out;

    unsigned short* wsW = (unsigned short*)d_ws;
    char* pub = (char*)d_ws + OFF_PUB;

    (void)hipMemsetAsync(pub, 0xFF, PUB_BYTES, stream);  // tags -> -1 (never valid)
    prep<<<144, 256, 0, stream>>>(W_emb, b_emb, W_ih, W_hh, b_ih, b_hh, wsW);
    lstm_main<<<256, 1024, 0, stream>>>(xin, wsW, out, pub);
}